// Round 7
// baseline (753.599 us; speedup 1.0000x reference)
//
#include <hip/hip_runtime.h>
#include <hip/hip_bf16.h>

// FP4 fake-quant MLP via MX-FP4 MFMA (16x16x128, unit block scales).
// Round-2 proven core (128x128 tile, BK=256 fp4, XOR chunk swizzle, 0 bank
// conflicts) + T3-minimum double-buffer: ONE barrier per K-tile, next-tile
// global_load_lds issued BEFORE compute so HBM/L2 latency hides under MFMA.

typedef float f32x4 __attribute__((ext_vector_type(4)));
typedef int   i32x4 __attribute__((ext_vector_type(4)));
typedef int   i32x8 __attribute__((ext_vector_type(8)));

#define AS1 __attribute__((address_space(1)))
#define AS3 __attribute__((address_space(3)))

// ---------- quant helpers ----------
__device__ __forceinline__ float scale_from_amax_bits(unsigned bits) {
    return fmaxf(__uint_as_float(bits) / 6.0f, 1e-12f);
}

// FP4 e2m1 code: idx 0..7 over grid {0,.5,1,1.5,2,3,4,6}, sign in bit 3.
// Compare chain == np.searchsorted(mids, xs, side='left') (ties -> lower mag).
__device__ __forceinline__ unsigned q4(float v, float inv_scale) {
    float xs = fabsf(v) * inv_scale;
    unsigned idx = 0;
    idx += (xs > 0.25f);
    idx += (xs > 0.75f);
    idx += (xs > 1.25f);
    idx += (xs > 1.75f);
    idx += (xs > 2.5f);
    idx += (xs > 3.5f);
    idx += (xs > 5.0f);
    return idx | ((v < 0.0f) ? 8u : 0u);
}

// ---------- tiny utility kernels ----------
__global__ void zero4_kernel(unsigned* p) {
    if (threadIdx.x < 4) p[threadIdx.x] = 0u;
}

__global__ void sentinel_kernel(float* out, long long n) {
    long long i = (long long)blockIdx.x * blockDim.x + threadIdx.x;
    long long stride = (long long)gridDim.x * blockDim.x;
    for (; i < n; i += stride) out[i] = 1e30f;
}

// ---------- fused absmax over the three input tensors (one launch) ----------
// blocks [0,512) -> in0/out[0]; [512,2560) -> in1/out[1]; [2560,4608) -> in2/out[3]
__global__ void absmax3_kernel(const float* __restrict__ in0, long long n0,
                               const float* __restrict__ in1, long long n1,
                               const float* __restrict__ in2, long long n2,
                               unsigned* __restrict__ out) {
    const float* in;
    long long n;
    unsigned* o;
    long long nb, b = blockIdx.x;
    if (b < 512)       { in = in0; n = n0; o = out + 0; b -= 0;    nb = 512;  }
    else if (b < 2560) { in = in1; n = n1; o = out + 1; b -= 512;  nb = 2048; }
    else               { in = in2; n = n2; o = out + 3; b -= 2560; nb = 2048; }

    long long i = (b * blockDim.x + threadIdx.x) * 4;
    long long stride = nb * blockDim.x * 4;
    float m = 0.0f;
    for (; i < n; i += stride) {
        float4 v = *(const float4*)&in[i];
        m = fmaxf(m, fmaxf(fmaxf(fabsf(v.x), fabsf(v.y)),
                           fmaxf(fabsf(v.z), fabsf(v.w))));
    }
    #pragma unroll
    for (int off = 32; off > 0; off >>= 1)
        m = fmaxf(m, __shfl_xor(m, off));
    __shared__ float smax[4];
    int lane = threadIdx.x & 63, w = threadIdx.x >> 6;
    if (lane == 0) smax[w] = m;
    __syncthreads();
    if (threadIdx.x == 0) {
        m = fmaxf(fmaxf(smax[0], smax[1]), fmaxf(smax[2], smax[3]));
        atomicMax(o, __float_as_uint(m));  // valid: all values >= 0
    }
}

// ---------- quantize f32 -> packed fp4 (n % 8 == 0), k-major nibbles ----------
__global__ void quant_pack_kernel(const float* __restrict__ in, long long n,
                                  const unsigned* __restrict__ amax,
                                  unsigned* __restrict__ out) {
    float inv = 1.0f / scale_from_amax_bits(*amax);
    long long i = ((long long)blockIdx.x * blockDim.x + threadIdx.x) * 8;
    long long stride = (long long)gridDim.x * blockDim.x * 8;
    for (; i < n; i += stride) {
        float4 a = *(const float4*)&in[i];
        float4 b = *(const float4*)&in[i + 4];
        unsigned u = q4(a.x, inv)        | (q4(a.y, inv) << 4)
                   | (q4(a.z, inv) << 8) | (q4(a.w, inv) << 12)
                   | (q4(b.x, inv) << 16)| (q4(b.y, inv) << 20)
                   | (q4(b.z, inv) << 24)| (q4(b.w, inv) << 28);
        out[i >> 3] = u;
    }
}

// ---------- quantize + transpose + pack: in [R][C] f32 -> out [C][R/2] bytes --
__global__ void quant_transpose_pack_kernel(const float* __restrict__ in, int R, int C,
                                            const unsigned* __restrict__ amax,
                                            unsigned char* __restrict__ out) {
    __shared__ float tile[64][65];
    float inv = 1.0f / scale_from_amax_bits(*amax);
    int t = threadIdx.x;
    int CT = C >> 6;
    int tc = blockIdx.x % CT;
    int tr = blockIdx.x / CT;
    int r0 = t >> 4;            // 0..15
    int c0 = (t & 15) * 4;      // 0..60
    #pragma unroll
    for (int it = 0; it < 4; ++it) {
        int r = r0 + it * 16;
        float4 v = *(const float4*)&in[(size_t)(tr * 64 + r) * C + tc * 64 + c0];
        tile[r][c0 + 0] = v.x;
        tile[r][c0 + 1] = v.y;
        tile[r][c0 + 2] = v.z;
        tile[r][c0 + 3] = v.w;
    }
    __syncthreads();
    int c = t >> 2;             // 0..63 : output row (= input column)
    int rch = (t & 3) * 16;     // k-chunk of 16 values
    unsigned u0 = 0, u1 = 0;
    #pragma unroll
    for (int j = 0; j < 8; ++j) u0 |= q4(tile[rch + j][c], inv) << (4 * j);
    #pragma unroll
    for (int j = 0; j < 8; ++j) u1 |= q4(tile[rch + 8 + j][c], inv) << (4 * j);
    uint2 o; o.x = u0; o.y = u1;
    *(uint2*)&out[(size_t)(tc * 64 + c) * (R >> 1) + (size_t)(tr * 32) + (rch >> 1)] = o;
}

// ---------- FP4 GEMM: C = (A @ BT^T) * (sa*sb) + bias, optional relu/amax ----
// Ap: [M][K/2] bytes (fp4 k-major); Bp: [N][K/2]; C: [M][N] f32.
// 128x128 tile, BK=256 fp4 (128B/row), 256 threads (2x2 waves of 64x64).
// mfma_scale_f32_16x16x128_f8f6f4, cbsz=blgp=4 (fp4), unit block scales.
// Double-buffered LDS (2 x 32KB): per K-tile, issue next-tile global_load_lds
// FIRST, then ds_read + MFMA on current buffer, then ONE __syncthreads
// (vmcnt(0)+lgkmcnt(0)+barrier). Load latency hides under the MFMA cluster.
// XOR chunk swizzle (slot = chunk ^ (row&7)) applied on BOTH the pre-swizzled
// global source and the ds_read (rule #21) -> 0 bank conflicts (measured r2).
template <int RELU, int FUSE_AMAX>
__global__ __launch_bounds__(256, 2)
void gemm_fp4_dbuf(const unsigned char* __restrict__ Ap,
                   const unsigned char* __restrict__ Bp,
                   float* __restrict__ C, const float* __restrict__ bias,
                   const unsigned* __restrict__ amaxA,
                   const unsigned* __restrict__ amaxB,
                   unsigned* __restrict__ amaxOut,
                   int M, int N, int K) {
    __shared__ alignas(16) unsigned char As[2][128 * 128];  // 32 KB
    __shared__ alignas(16) unsigned char Bs[2][128 * 128];  // 32 KB
    __shared__ float smax[4];

    // bijective XCD swizzle (gridDim.x % 8 == 0 by construction)
    int nwg = gridDim.x;
    int cpx = nwg >> 3;
    int wg = (blockIdx.x & 7) * cpx + (blockIdx.x >> 3);
    int MT = M >> 7;
    int tm = wg % MT;
    int tn = wg / MT;

    int tid = threadIdx.x;
    int lane = tid & 63;
    int wid = tid >> 6;                 // 0..3
    int wr = wid >> 1, wc = wid & 1;    // 2x2 wave grid, each owns 64x64

    size_t Kb = (size_t)(K >> 1);       // bytes per packed row

    // Staging: per K-tile each matrix tile is 128 rows x 128B. One instr:
    // 64 lanes x 16B = 8 rows; lane covers row (lane>>3), chunk (lane&7).
    // Global source chunk pre-swizzled: cs = (lane&7) ^ (row&7), with
    // row&7 == (lane>>3)&7 (row bases are multiples of 8).
    int cs = ((lane & 7) ^ ((lane >> 3) & 7)) << 4;
    int srow = wid * 32 + (lane >> 3);
    const unsigned char* Abase = Ap + (size_t)(tm * 128 + srow) * Kb + cs;
    const unsigned char* Bbase = Bp + (size_t)(tn * 128 + srow) * Kb + cs;
    char* AsB = (char*)As;
    char* BsB = (char*)Bs;
    int ldsOff = wid * 4096;            // wave's 32 rows x 128B

#define STAGE(d, kt)                                                          \
    do {                                                                      \
        _Pragma("unroll")                                                     \
        for (int i_ = 0; i_ < 4; ++i_) {                                      \
            __builtin_amdgcn_global_load_lds(                                 \
                (const AS1 void*)(Abase + (size_t)(kt) * 128 +                \
                                  (size_t)(i_ * 8) * Kb),                     \
                (AS3 void*)(AsB + ((d) << 14) + ldsOff + i_ * 1024),          \
                16, 0, 0);                                                    \
            __builtin_amdgcn_global_load_lds(                                 \
                (const AS1 void*)(Bbase + (size_t)(kt) * 128 +                \
                                  (size_t)(i_ * 8) * Kb),                     \
                (AS3 void*)(BsB + ((d) << 14) + ldsOff + i_ * 1024),          \
                16, 0, 0);                                                    \
        }                                                                     \
    } while (0)

    f32x4 acc[4][4] = {};
    int rrA = wr * 64 + (lane & 15);    // fragment row in A tile (+ mi*16)
    int rrB = wc * 64 + (lane & 15);    // fragment row in B tile (+ ni*16)

    int KT = K >> 8;                    // K-tiles of 256 fp4

    // prologue: stage tile 0 into buffer 0
    STAGE(0, 0);
    __syncthreads();

    for (int t = 0; t < KT; ++t) {
        int d = t & 1;
        // issue next tile's loads first (into the other buffer)
        if (t + 1 < KT) STAGE(d ^ 1, t + 1);
        __builtin_amdgcn_sched_barrier(0);  // pin STAGE issue before ds_reads

        const char* Aq = AsB + (d << 14);
        const char* Bq = BsB + (d << 14);
        #pragma unroll
        for (int ks = 0; ks < 2; ++ks) {
            // global 16B-chunk index within the row: ks*4 + (lane>>4);
            // LDS slot = chunk ^ (row&7), row&7 == lane&7 for all mi/ni.
            int slotOff = ((ks * 4 + (lane >> 4)) ^ (lane & 7)) << 4;
            i32x8 a8[4], b8[4];
            #pragma unroll
            for (int mi = 0; mi < 4; ++mi) {
                i32x4 v = *(const i32x4*)(Aq + (rrA + mi * 16) * 128 + slotOff);
                a8[mi] = i32x8{v[0], v[1], v[2], v[3], 0, 0, 0, 0};
            }
            #pragma unroll
            for (int ni = 0; ni < 4; ++ni) {
                i32x4 v = *(const i32x4*)(Bq + (rrB + ni * 16) * 128 + slotOff);
                b8[ni] = i32x8{v[0], v[1], v[2], v[3], 0, 0, 0, 0};
            }
            #pragma unroll
            for (int mi = 0; mi < 4; ++mi)
                #pragma unroll
                for (int ni = 0; ni < 4; ++ni)
                    acc[mi][ni] = __builtin_amdgcn_mfma_scale_f32_16x16x128_f8f6f4(
                        a8[mi], b8[ni], acc[mi][ni],
                        4, 4,                    // cbsz=fp4, blgp=fp4
                        0, 0x7f7f7f7f,           // scale_a: E8M0 1.0
                        0, 0x7f7f7f7f);          // scale_b: E8M0 1.0
        }
        // one barrier per K-tile: drains vmcnt(0) (next tile staged) and
        // syncs all waves (done reading buffer d before t+2 overwrites it).
        __syncthreads();
    }
#undef STAGE

    float sa = scale_from_amax_bits(*amaxA);
    float sb = scale_from_amax_bits(*amaxB);
    float s = sa * sb;
    float vmax = 0.0f;
    int rowBase = tm * 128 + wr * 64 + (lane >> 4) * 4;
    int colBase = tn * 128 + wc * 64 + (lane & 15);
    #pragma unroll
    for (int mi = 0; mi < 4; ++mi) {
        #pragma unroll
        for (int ni = 0; ni < 4; ++ni) {
            int col = colBase + ni * 16;
            float bv = bias[col];
            int row = rowBase + mi * 16;
            #pragma unroll
            for (int r = 0; r < 4; ++r) {
                float v = acc[mi][ni][r] * s + bv;
                if (RELU) v = fmaxf(v, 0.0f);
                if (FUSE_AMAX) vmax = fmaxf(vmax, fabsf(v));
                C[(size_t)(row + r) * N + col] = v;
            }
        }
    }
    if (FUSE_AMAX) {
        #pragma unroll
        for (int off = 32; off > 0; off >>= 1)
            vmax = fmaxf(vmax, __shfl_xor(vmax, off));
        if (lane == 0) smax[wid] = vmax;
        __syncthreads();
        if (tid == 0) {
            vmax = fmaxf(fmaxf(smax[0], smax[1]), fmaxf(smax[2], smax[3]));
            atomicMax(amaxOut, __float_as_uint(vmax));
        }
    }
}

// ---------- launch ----------
extern "C" void kernel_launch(void* const* d_in, const int* in_sizes, int n_in,
                              void* d_out, int out_size, void* d_ws, size_t ws_size,
                              hipStream_t stream) {
    const float* x  = (const float*)d_in[0];
    const float* w1 = (const float*)d_in[1];
    const float* b1 = (const float*)d_in[2];
    const float* w2 = (const float*)d_in[3];
    const float* b2 = (const float*)d_in[4];
    float* out = (float*)d_out;

    const int B = 4096, DIN = 4096, DH = 16384, DOUT = 4096;

    // workspace layout (packed fp4 operands)
    const size_t off_amax = 0;                                    // 4 uints
    const size_t off_Xq   = 256;                                  // 8 MB
    const size_t off_W    = off_Xq + (size_t)B * DIN / 2;         // 32 MB
    const size_t off_h    = off_W + (size_t)DIN * DH / 2;         // 256 MB f32
    const size_t off_Hq   = off_h + (size_t)B * DH * 4;           // 32 MB
    const size_t needed   = off_Hq + (size_t)B * DH / 2;

    if (ws_size < needed) {
        sentinel_kernel<<<2048, 256, 0, stream>>>(out, (long long)out_size);
        return;
    }

    char* ws = (char*)d_ws;
    unsigned* amax = (unsigned*)(ws + off_amax);  // [0]=x [1]=w1 [2]=h [3]=w2
    unsigned char* Xq = (unsigned char*)(ws + off_Xq);
    unsigned char* Wq = (unsigned char*)(ws + off_W);
    float*         h  = (float*)(ws + off_h);
    unsigned char* Hq = (unsigned char*)(ws + off_Hq);

    zero4_kernel<<<1, 64, 0, stream>>>(amax);

    // fused absmax of x, w1, w2 (one launch)
    absmax3_kernel<<<4608, 256, 0, stream>>>(x, (long long)B * DIN,
                                             w1, (long long)DIN * DH,
                                             w2, (long long)DH * DOUT, amax);

    quant_pack_kernel<<<2048, 256, 0, stream>>>(x, (long long)B * DIN, amax + 0,
                                                (unsigned*)Xq);
    quant_transpose_pack_kernel<<<(DIN / 64) * (DH / 64), 256, 0, stream>>>(
        w1, DIN, DH, amax + 1, Wq);

    // h = relu(Q(x) @ Q(w1) + b1), fused absmax(h) -> amax[2]
    gemm_fp4_dbuf<1, 1><<<(B / 128) * (DH / 128), 256, 0, stream>>>(
        Xq, Wq, h, b1, amax + 0, amax + 1, amax + 2, B, DH, DIN);

    quant_pack_kernel<<<2048, 256, 0, stream>>>(h, (long long)B * DH, amax + 2,
                                                (unsigned*)Hq);
    quant_transpose_pack_kernel<<<(DH / 64) * (DOUT / 64), 256, 0, stream>>>(
        w2, DH, DOUT, amax + 3, Wq);

    // out = Q(h) @ Q(w2) + b2
    gemm_fp4_dbuf<0, 0><<<(B / 128) * (DOUT / 128), 256, 0, stream>>>(
        Hq, Wq, out, b2, amax + 2, amax + 3, nullptr, B, DOUT, DH);
}